// Round 10
// baseline (566.977 us; speedup 1.0000x reference)
//
#include <hip/hip_runtime.h>
#include <stdint.h>

#define B_ 4
#define L_ 4096
#define D_ 1024
#define C_ 2048
#define M_ (B_ * L_)  // 16384

typedef __attribute__((ext_vector_type(8))) short s16x8;
typedef __attribute__((ext_vector_type(4))) float fx4;
typedef __attribute__((ext_vector_type(4))) unsigned int ux4;
typedef unsigned short bfu;  // bf16 bits

__device__ __forceinline__ float bits2f(short s) {
  return __uint_as_float(((uint32_t)(unsigned short)s) << 16);
}
__device__ __forceinline__ bfu f2bf(float f) {
  uint32_t u = __float_as_uint(f);
  uint32_t r = (u + 0x7FFFu + ((u >> 16) & 1u)) >> 16;  // RNE
  return (bfu)r;
}
__device__ __forceinline__ uint32_t pk_bf16(float lo, float hi) {
  uint32_t r;
  asm("v_cvt_pk_bf16_f32 %0, %1, %2" : "=v"(r) : "v"(lo), "v"(hi));
  return r;
}

__device__ __forceinline__ void gload_lds16(const void* g, void* l) {
  __builtin_amdgcn_global_load_lds(
      (const __attribute__((address_space(1))) void*)g,
      (__attribute__((address_space(3))) void*)l, 16, 0, 0);
}

#define BAR() asm volatile("s_barrier" ::: "memory")
#define LGKM0() asm volatile("s_waitcnt lgkmcnt(0)" ::: "memory")
#define VMW15() asm volatile("s_waitcnt vmcnt(15)" ::: "memory")
#define VMW8() asm volatile("s_waitcnt vmcnt(8)" ::: "memory")
#define VMW4() asm volatile("s_waitcnt vmcnt(4)" ::: "memory")
#define VMW0() asm volatile("s_waitcnt vmcnt(0)" ::: "memory")

// ---------------- fp32 -> bf16 bulk convert ----------------
__global__ __launch_bounds__(256) void cvt_f32_bf16(const float* __restrict__ in,
                                                    bfu* __restrict__ out, int n8) {
  const int stride = gridDim.x * blockDim.x;
  for (int i = blockIdx.x * blockDim.x + threadIdx.x; i < n8; i += stride) {
    const size_t off = (size_t)i * 8;
    fx4 a = *(const fx4*)(in + off);
    fx4 b = *(const fx4*)(in + off + 4);
    s16x8 o;
#pragma unroll
    for (int j = 0; j < 4; j++) {
      o[j] = (short)f2bf(a[j]);
      o[j + 4] = (short)f2bf(b[j]);
    }
    *reinterpret_cast<s16x8*>(out + off) = o;
  }
}

// ---------------- transpose + fp32->bf16 convert: out[c][r] = in[r][c] ----------------
template <int R, int CC>
__global__ __launch_bounds__(256) void transpose_cvt(const float* __restrict__ in,
                                                     bfu* __restrict__ out) {
  __shared__ float tile[32][33];
  const int bx = blockIdx.x, by = blockIdx.y, tx = threadIdx.x;
  for (int j = threadIdx.y; j < 32; j += 8)
    tile[j][tx] = in[(size_t)(by * 32 + j) * CC + bx * 32 + tx];
  __syncthreads();
  for (int j = threadIdx.y; j < 32; j += 8)
    out[(size_t)(bx * 32 + j) * R + by * 32 + tx] = f2bf(tile[tx][j]);
}

// ------- conv tables: cwb[t4*1024+c2] = 2xbf16 taps; cwb[4096+c2] = 2xbf16 cb --------
__global__ __launch_bounds__(256) void prep_cw2(const float* __restrict__ cw,
                                                const float* __restrict__ cb,
                                                uint32_t* __restrict__ cwb) {
  const int c = blockIdx.x * 256 + threadIdx.x;  // ch-pair 0..1023
#pragma unroll
  for (int t4 = 0; t4 < 4; t4++)
    cwb[t4 * 1024 + c] =
        ((uint32_t)f2bf(cw[t4 * C_ + 2 * c + 1]) << 16) | f2bf(cw[t4 * C_ + 2 * c]);
  cwb[4096 + c] = ((uint32_t)f2bf(cb[2 * c + 1]) << 16) | f2bf(cb[2 * c]);
}

// =================== 256x256 8-phase GEMM pieces ===================
// LDS buffer (elements): A-kh0 @0, A-kh1 @8192, B-kh0 @16384, B-kh1 @24576;
// buf1 = +32768.  Rows are 64 B (32 bf16).  Swizzle involution (both sides):
// XOR bits 4-5 of the linear byte address with row bits 1-2.

template <int KD>
__device__ __forceinline__ void stage_half(const bfu* __restrict__ Mt, int r0, int kb,
                                           bfu* region, int t) {
#pragma unroll
  for (int h = 0; h < 2; h++) {
    const int u = t + h * 512;
    const int srow = u >> 2;
    const int sslot = (u & 3) ^ ((srow >> 1) & 3);
    gload_lds16(Mt + (size_t)(r0 + srow) * KD + kb + sslot * 8, region + u * 8);
  }
}

#define LF(bytoff) \
  (*reinterpret_cast<const s16x8*>(reinterpret_cast<const char*>(lds) + (bytoff)))

// ---------------- plain GEMM (GEMM1): R7 structure, unchanged ----------------
template <int MM, int N, int KD, bool OUT_BF16>
__global__ __launch_bounds__(512, 2) void gemm256(const bfu* __restrict__ A,
                                                  const bfu* __restrict__ Bt,
                                                  const float* __restrict__ bias,
                                                  void* __restrict__ Cptr) {
  __shared__ bfu lds[2 * 4 * 8192];  // 128 KiB
  const int t = threadIdx.x;
  const int lane = t & 63, wid = t >> 6;
  const int wr = wid >> 2, wc = wid & 3;
  const int lr = lane & 15, lg = lane >> 4;
  const int cpx = gridDim.x >> 3;
  const int li = (blockIdx.x & 7) * cpx + (blockIdx.x >> 3);
  const int row0 = (li % (MM / 256)) * 256;
  const int col0 = (li / (MM / 256)) * 256;
  constexpr int ntk = KD / 64;
  const int abase = ((wr * 128 + lr) * 64 + lg * 16) ^ (((lr >> 1) & 3) << 4);
  const int bbase = ((wc * 64 + lr) * 64 + lg * 16) ^ (((lr >> 1) & 3) << 4);

  fx4 acc[8][4] = {};

  stage_half<KD>(A, row0, 0, lds + 0, t);
  stage_half<KD>(Bt, col0, 0, lds + 16384, t);
  stage_half<KD>(A, row0, 32, lds + 8192, t);
  stage_half<KD>(Bt, col0, 32, lds + 24576, t);
  stage_half<KD>(A, row0, 64, lds + 32768 + 0, t);
  stage_half<KD>(Bt, col0, 64, lds + 32768 + 16384, t);
  VMW8();
  BAR();

  for (int tau = 0; tau < ntk; ++tau) {
    const int cbb = (tau & 1) ? 65536 : 0;
    bfu* nb_ = (tau & 1) ? lds : lds + 32768;
    s16x8 af[4], bf4[4];

#pragma unroll
    for (int m = 0; m < 4; m++) af[m] = LF(cbb + abase + m * 1024);
#pragma unroll
    for (int n = 0; n < 4; n++) bf4[n] = LF(cbb + 32768 + bbase + n * 1024);
    if (tau + 1 < ntk) stage_half<KD>(A, row0, (tau + 1) * 64 + 32, nb_ + 8192, t);
    BAR();
    LGKM0();
    __builtin_amdgcn_s_setprio(1);
#pragma unroll
    for (int m = 0; m < 4; m++)
#pragma unroll
      for (int n = 0; n < 4; n++)
        acc[m][n] = __builtin_amdgcn_mfma_f32_16x16x32_bf16(af[m], bf4[n], acc[m][n], 0, 0, 0);
    __builtin_amdgcn_s_setprio(0);
    BAR();

#pragma unroll
    for (int m = 0; m < 4; m++) af[m] = LF(cbb + abase + 4096 + m * 1024);
    if (tau + 1 < ntk) stage_half<KD>(Bt, col0, (tau + 1) * 64 + 32, nb_ + 24576, t);
    BAR();
    LGKM0();
    __builtin_amdgcn_s_setprio(1);
#pragma unroll
    for (int m = 0; m < 4; m++)
#pragma unroll
      for (int n = 0; n < 4; n++)
        acc[m + 4][n] = __builtin_amdgcn_mfma_f32_16x16x32_bf16(af[m], bf4[n], acc[m + 4][n], 0, 0, 0);
    __builtin_amdgcn_s_setprio(0);
    if (tau < ntk - 1) VMW8();
    else VMW0();
    BAR();

#pragma unroll
    for (int m = 0; m < 4; m++) af[m] = LF(cbb + 16384 + abase + m * 1024);
#pragma unroll
    for (int n = 0; n < 4; n++) bf4[n] = LF(cbb + 49152 + bbase + n * 1024);
    if (tau + 2 < ntk) stage_half<KD>(A, row0, (tau + 2) * 64, lds + (cbb >> 1), t);
    BAR();
    LGKM0();
    __builtin_amdgcn_s_setprio(1);
#pragma unroll
    for (int m = 0; m < 4; m++)
#pragma unroll
      for (int n = 0; n < 4; n++)
        acc[m][n] = __builtin_amdgcn_mfma_f32_16x16x32_bf16(af[m], bf4[n], acc[m][n], 0, 0, 0);
    __builtin_amdgcn_s_setprio(0);
    BAR();

#pragma unroll
    for (int m = 0; m < 4; m++) af[m] = LF(cbb + 16384 + abase + 4096 + m * 1024);
    if (tau + 2 < ntk) stage_half<KD>(Bt, col0, (tau + 2) * 64, lds + (cbb >> 1) + 16384, t);
    BAR();
    LGKM0();
    __builtin_amdgcn_s_setprio(1);
#pragma unroll
    for (int m = 0; m < 4; m++)
#pragma unroll
      for (int n = 0; n < 4; n++)
        acc[m + 4][n] = __builtin_amdgcn_mfma_f32_16x16x32_bf16(af[m], bf4[n], acc[m + 4][n], 0, 0, 0);
    __builtin_amdgcn_s_setprio(0);
    if (tau < ntk - 2) VMW8();
    else if (tau == ntk - 2) VMW4();
    BAR();
  }

  float bv[4];
#pragma unroll
  for (int n = 0; n < 4; n++) bv[n] = bias[col0 + wc * 64 + n * 16 + lr];
#pragma unroll
  for (int m = 0; m < 8; m++)
#pragma unroll
    for (int n = 0; n < 4; n++)
#pragma unroll
      for (int r = 0; r < 4; r++) {
        const int row = row0 + wr * 128 + m * 16 + lg * 4 + r;
        const int col = col0 + wc * 64 + n * 16 + lr;
        const float v = acc[m][n][r] + bv[n];
        if constexpr (OUT_BF16)
          ((bfu*)Cptr)[(size_t)row * N + col] = f2bf(v);
        else
          ((float*)Cptr)[(size_t)row * N + col] = v;
      }
}

// ---------------- fused GEMM2: out = conv(xe) @ W_cmp + b_cmp ----------------
// A-staging computes y on the fly with the EXACT linear-chunk mapping of
// global_load_lds: thread covers chunks u = tt + q*256 of its region (t<256:
// kh0, else kh1), u = row (u>>2) x 8 cols at sslot*8, sslot=(tt&3)^((tt>>3)&3)
// (per-thread constant).  Wave writes 64 consecutive 16B chunks -> 0 conflicts.
// q01 written at P3 (x batch issued prev P4-end), q23 at P4 (issued mid-P3).

#define CONVX(xa, TILE, QB)                                                       \
  {                                                                               \
    const int c_ = (TILE)*64 + koff + sslot * 8;                                  \
    _Pragma("unroll") for (int qi = 0; qi < 2; qi++) {                            \
      const int rb_ = (tt >> 2) + ((QB) + qi) * 64;                               \
      _Pragma("unroll") for (int t4 = 0; t4 < 4; t4++) {                          \
        int rs_ = rb_ - 3 + t4;                                                   \
        if ((QB) == 0 && zh && rs_ < 0) rs_ = 0;                                  \
        xa[qi * 4 + t4] =                                                         \
            *reinterpret_cast<const ux4*>(xe + (size_t)(row0 + rs_) * C_ + c_);   \
      }                                                                           \
    }                                                                             \
  }

#define CONVW(TILE)                                                               \
  {                                                                               \
    const int cp0_ = (TILE)*32 + (koff >> 1) + sslot * 4;                         \
    _Pragma("unroll") for (int t4 = 0; t4 < 4; t4++)                              \
        wv[t4] = *reinterpret_cast<const ux4*>(cwb + t4 * 1024 + cp0_);           \
    cbv = *reinterpret_cast<const ux4*>(cwb + 4096 + cp0_);                       \
  }

#define CONVWR(nbptr, xa, QB)                                                     \
  {                                                                               \
    bfu* reg_ = (nbptr) + ((t < 256) ? 0 : 8192);                                 \
    _Pragma("unroll") for (int qi = 0; qi < 2; qi++) {                            \
      ux4 od_;                                                                    \
      _Pragma("unroll") for (int d = 0; d < 4; d++) {                             \
        float lo = __uint_as_float(cbv[d] << 16);                                 \
        float hi = __uint_as_float(cbv[d] & 0xffff0000u);                         \
        _Pragma("unroll") for (int t4 = 0; t4 < 4; t4++) {                        \
          uint32_t xv = xa[qi * 4 + t4][d];                                       \
          if ((QB) == 0 && qi == 0 && zh && ((tt >> 2) < 3 - t4)) xv = 0;         \
          const uint32_t wvv = wv[t4][d];                                         \
          lo = fmaf(__uint_as_float(xv << 16), __uint_as_float(wvv << 16), lo);   \
          hi = fmaf(__uint_as_float(xv & 0xffff0000u),                            \
                    __uint_as_float(wvv & 0xffff0000u), hi);                      \
        }                                                                         \
        od_[d] = pk_bf16(lo, hi);                                                 \
      }                                                                           \
      *reinterpret_cast<ux4*>(reg_ + (tt + ((QB) + qi) * 256) * 8) = od_;         \
    }                                                                             \
  }

template <int MM, int N, int KD>
__global__ __launch_bounds__(512, 2) void gemm256_conv(
    const bfu* __restrict__ xe, const bfu* __restrict__ Bt,
    const uint32_t* __restrict__ cwb, const float* __restrict__ bias,
    float* __restrict__ Cptr) {
  __shared__ bfu lds[2 * 4 * 8192];  // 128 KiB
  const int t = threadIdx.x;
  const int lane = t & 63, wid = t >> 6;
  const int wr = wid >> 2, wc = wid & 3;
  const int lr = lane & 15, lg = lane >> 4;
  const int cpx = gridDim.x >> 3;
  const int li = (blockIdx.x & 7) * cpx + (blockIdx.x >> 3);
  const int row0 = (li % (MM / 256)) * 256;
  const int col0 = (li / (MM / 256)) * 256;
  constexpr int ntk = KD / 64;
  const int abase = ((wr * 128 + lr) * 64 + lg * 16) ^ (((lr >> 1) & 3) << 4);
  const int bbase = ((wc * 64 + lr) * 64 + lg * 16) ^ (((lr >> 1) & 3) << 4);
  const int tt = t & 255;
  const int koff = (t < 256) ? 0 : 32;
  const int sslot = (tt & 3) ^ ((tt >> 3) & 3);
  const bool zh = (row0 & (L_ - 1)) == 0;

  fx4 acc[8][4] = {};
  ux4 x1[8], x2[8], wv[4], cbv;

  // -------- prologue: conv-stage A(0); B(0) halves + B(1)kh0; preload b1(tile1).
  CONVW(0);
  CONVX(x1, 0, 0);
  CONVX(x2, 0, 2);
  stage_half<KD>(Bt, col0, 0, lds + 16384, t);
  stage_half<KD>(Bt, col0, 32, lds + 24576, t);
  stage_half<KD>(Bt, col0, 64, lds + 32768 + 16384, t);
  CONVWR(lds, x1, 0);   // auto-vmcnt waits cover x1/wv
  CONVWR(lds, x2, 2);
  CONVW(1);
  CONVX(x1, 1, 0);      // 13 loads for tau=0's P3
  VMW15();              // drains B(0); leaves b1(13)+B(1)kh0(2)
  LGKM0();
  BAR();

  for (int tau = 0; tau < ntk; ++tau) {
    const int cbb = (tau & 1) ? 65536 : 0;
    bfu* nb_ = (tau & 1) ? lds : lds + 32768;
    s16x8 af[4], bf4[4];

    // ---- P1: kh0, m0-3 x n0-3
#pragma unroll
    for (int m = 0; m < 4; m++) af[m] = LF(cbb + abase + m * 1024);
#pragma unroll
    for (int n = 0; n < 4; n++) bf4[n] = LF(cbb + 32768 + bbase + n * 1024);
    BAR();
    LGKM0();
    __builtin_amdgcn_s_setprio(1);
#pragma unroll
    for (int m = 0; m < 4; m++)
#pragma unroll
      for (int n = 0; n < 4; n++)
        acc[m][n] = __builtin_amdgcn_mfma_f32_16x16x32_bf16(af[m], bf4[n], acc[m][n], 0, 0, 0);
    __builtin_amdgcn_s_setprio(0);
    BAR();

    // ---- P2: kh0, m4-7 | stage (tau+1).B-kh1 -> nb_
#pragma unroll
    for (int m = 0; m < 4; m++) af[m] = LF(cbb + abase + 4096 + m * 1024);
    if (tau + 1 < ntk) stage_half<KD>(Bt, col0, (tau + 1) * 64 + 32, nb_ + 24576, t);
    BAR();
    LGKM0();
    __builtin_amdgcn_s_setprio(1);
#pragma unroll
    for (int m = 0; m < 4; m++)
#pragma unroll
      for (int n = 0; n < 4; n++)
        acc[m + 4][n] = __builtin_amdgcn_mfma_f32_16x16x32_bf16(af[m], bf4[n], acc[m + 4][n], 0, 0, 0);
    __builtin_amdgcn_s_setprio(0);
    BAR();

    // ---- P3: kh1, m0-3 x n0-3 | conv-write q01 of A(tau+1) | issue x2(tau+1)
#pragma unroll
    for (int m = 0; m < 4; m++) af[m] = LF(cbb + 16384 + abase + m * 1024);
#pragma unroll
    for (int n = 0; n < 4; n++) bf4[n] = LF(cbb + 49152 + bbase + n * 1024);
    BAR();
    if (tau + 1 < ntk) {
      CONVWR(nb_, x1, 0);
      CONVX(x2, tau + 1, 2);
    }
    LGKM0();
    __builtin_amdgcn_s_setprio(1);
#pragma unroll
    for (int m = 0; m < 4; m++)
#pragma unroll
      for (int n = 0; n < 4; n++)
        acc[m][n] = __builtin_amdgcn_mfma_f32_16x16x32_bf16(af[m], bf4[n], acc[m][n], 0, 0, 0);
    __builtin_amdgcn_s_setprio(0);
    BAR();

    // ---- P4: kh1, m4-7 | stage (tau+2).B-kh0 | conv-write q23 | issue b1(tau+2)
#pragma unroll
    for (int m = 0; m < 4; m++) af[m] = LF(cbb + 16384 + abase + 4096 + m * 1024);
    if (tau + 2 < ntk) stage_half<KD>(Bt, col0, (tau + 2) * 64, lds + (cbb >> 1) + 16384, t);
    BAR();
    if (tau + 1 < ntk) CONVWR(nb_, x2, 2);
    LGKM0();
    __builtin_amdgcn_s_setprio(1);
#pragma unroll
    for (int m = 0; m < 4; m++)
#pragma unroll
      for (int n = 0; n < 4; n++)
        acc[m + 4][n] = __builtin_amdgcn_mfma_f32_16x16x32_bf16(af[m], bf4[n], acc[m + 4][n], 0, 0, 0);
    __builtin_amdgcn_s_setprio(0);
    if (tau + 2 < ntk) {
      CONVW(tau + 2);
      CONVX(x1, tau + 2, 0);
      VMW15();  // leaves b1(13)+B-kh0(2); drains B-kh1(tau+1) (needed tau+1 P3)
    } else {
      VMW0();
    }
    BAR();
  }

  // epilogue
  float bv[4];
#pragma unroll
  for (int n = 0; n < 4; n++) bv[n] = bias[col0 + wc * 64 + n * 16 + lr];
#pragma unroll
  for (int m = 0; m < 8; m++)
#pragma unroll
    for (int n = 0; n < 4; n++)
#pragma unroll
      for (int r = 0; r < 4; r++) {
        const int row = row0 + wr * 128 + m * 16 + lg * 4 + r;
        const int col = col0 + wc * 64 + n * 16 + lr;
        Cptr[(size_t)row * N + col] = acc[m][n][r] + bv[n];
      }
}

extern "C" void kernel_launch(void* const* d_in, const int* in_sizes, int n_in,
                              void* d_out, int out_size, void* d_ws, size_t ws_size,
                              hipStream_t stream) {
  const float* x = (const float*)d_in[0];
  const float* W_exp = (const float*)d_in[1];
  const float* b_exp = (const float*)d_in[2];
  const float* cw = (const float*)d_in[3];
  const float* cb = (const float*)d_in[4];
  const float* W_cmp = (const float*)d_in[5];
  const float* b_cmp = (const float*)d_in[6];
  float* out = (float*)d_out;

  char* ws = (char*)d_ws;
  bfu* wexp_t = (bfu*)(ws);                   // [C][D] bf16, 4 MiB
  bfu* wcmp_t = (bfu*)(ws + (4u << 20));      // [D][C] bf16, 4 MiB
  bfu* xb = (bfu*)(ws + (8u << 20));          // [M][D] bf16, 32 MiB
  bfu* xe = (bfu*)(ws + (40u << 20));         // [M][C] bf16, 64 MiB
  uint32_t* cwb = (uint32_t*)(ws + (104u << 20));  // [5][1024] dwords, 20 KiB

  cvt_f32_bf16<<<2048, 256, 0, stream>>>(x, xb, M_ * D_ / 8);
  transpose_cvt<D_, C_><<<dim3(C_ / 32, D_ / 32), dim3(32, 8), 0, stream>>>(W_exp, wexp_t);
  transpose_cvt<C_, D_><<<dim3(D_ / 32, C_ / 32), dim3(32, 8), 0, stream>>>(W_cmp, wcmp_t);
  prep_cw2<<<4, 256, 0, stream>>>(cw, cb, cwb);
  // expand GEMM: xe = x @ W_exp + b_exp
  gemm256<M_, C_, D_, true><<<512, 512, 0, stream>>>(xb, wexp_t, b_exp, xe);
  // fused compress GEMM: out = conv(xe) @ W_cmp + b_cmp  (conv in A-staging)
  gemm256_conv<M_, D_, C_><<<256, 512, 0, stream>>>(xe, wcmp_t, cwb, b_cmp, out);
}

// Round 11
// 200.643 us; speedup vs baseline: 2.8258x; 2.8258x over previous
//
#include <hip/hip_runtime.h>
#include <stdint.h>

#define B_ 4
#define L_ 4096
#define D_ 1024
#define C_ 2048
#define M_ (B_ * L_)  // 16384
#define LCH 16        // conv l-chunk per block

typedef __attribute__((ext_vector_type(8))) short s16x8;
typedef __attribute__((ext_vector_type(4))) float fx4;
typedef unsigned short bfu;  // bf16 bits

__device__ __forceinline__ float bits2f(short s) {
  return __uint_as_float(((uint32_t)(unsigned short)s) << 16);
}
__device__ __forceinline__ bfu f2bf(float f) {
  uint32_t u = __float_as_uint(f);
  uint32_t r = (u + 0x7FFFu + ((u >> 16) & 1u)) >> 16;  // RNE
  return (bfu)r;
}

__device__ __forceinline__ void gload_lds16(const void* g, void* l) {
  __builtin_amdgcn_global_load_lds(
      (const __attribute__((address_space(1))) void*)g,
      (__attribute__((address_space(3))) void*)l, 16, 0, 0);
}

#define BAR() asm volatile("s_barrier" ::: "memory")
#define LGKM0() asm volatile("s_waitcnt lgkmcnt(0)" ::: "memory")
#define VMW8() asm volatile("s_waitcnt vmcnt(8)" ::: "memory")
#define VMW4() asm volatile("s_waitcnt vmcnt(4)" ::: "memory")
#define VMW0() asm volatile("s_waitcnt vmcnt(0)" ::: "memory")

// ---------------- fp32 -> bf16 bulk convert ----------------
__global__ __launch_bounds__(256) void cvt_f32_bf16(const float* __restrict__ in,
                                                    bfu* __restrict__ out, int n8) {
  const int stride = gridDim.x * blockDim.x;
  for (int i = blockIdx.x * blockDim.x + threadIdx.x; i < n8; i += stride) {
    const size_t off = (size_t)i * 8;
    fx4 a = *(const fx4*)(in + off);
    fx4 b = *(const fx4*)(in + off + 4);
    s16x8 o;
#pragma unroll
    for (int j = 0; j < 4; j++) {
      o[j] = (short)f2bf(a[j]);
      o[j + 4] = (short)f2bf(b[j]);
    }
    *reinterpret_cast<s16x8*>(out + off) = o;
  }
}

// ---------------- transpose + fp32->bf16 convert: out[c][r] = in[r][c] ----------------
template <int R, int CC>
__global__ __launch_bounds__(256) void transpose_cvt(const float* __restrict__ in,
                                                     bfu* __restrict__ out) {
  __shared__ float tile[32][33];
  const int bx = blockIdx.x, by = blockIdx.y, tx = threadIdx.x;
  for (int j = threadIdx.y; j < 32; j += 8)
    tile[j][tx] = in[(size_t)(by * 32 + j) * CC + bx * 32 + tx];
  __syncthreads();
  for (int j = threadIdx.y; j < 32; j += 8)
    out[(size_t)(bx * 32 + j) * R + by * 32 + tx] = f2bf(tile[tx][j]);
}

// =================== 256x256 8-phase GEMM ===================
// LDS bytes: buf0 { A-kh0 @0, A-kh1 @16384, B-kh0 @32768, B-kh1 @49152 };
// buf1 = +65536.  Rows are 64 B (32 bf16).  Swizzle involution (both sides):
// XOR byte bits 4-5 with row bits 1-2.  R11: static dual-buffer unroll —
// 4 per-thread base pointers, all ds_read offsets compile-time immediates.

template <int KD>
__device__ __forceinline__ void stage_half(const bfu* __restrict__ Mt, int r0, int kb,
                                           bfu* region, int t) {
#pragma unroll
  for (int h = 0; h < 2; h++) {
    const int u = t + h * 512;
    const int srow = u >> 2;
    const int sslot = (u & 3) ^ ((srow >> 1) & 3);
    gload_lds16(Mt + (size_t)(r0 + srow) * KD + kb + sslot * 8, region + u * 8);
  }
}

#define LF2(p, off) (*reinterpret_cast<const s16x8*>((p) + (off)))

// One K-tile = 4 phases; PA/PB = char* frag bases (this buffer), CBEL/NBEL =
// bfu* element bases of current/next buffer (stage targets).  tu = tile index.
#define KTILE(PA, PB, CBEL, NBEL, tu)                                                  \
  {                                                                                    \
    s16x8 af[4], bf4[4];                                                               \
    /* P1: kh0 rows 0-63 x n0-3 | stage (tu+1).A-kh1 */                                \
    _Pragma("unroll") for (int m = 0; m < 4; m++) af[m] = LF2(PA, m * 1024);           \
    _Pragma("unroll") for (int n = 0; n < 4; n++) bf4[n] = LF2(PB, n * 1024);          \
    if ((tu) + 1 < ntk) stage_half<KD>(A, row0, ((tu) + 1) * 64 + 32, (NBEL) + 8192, t);\
    BAR();                                                                             \
    LGKM0();                                                                           \
    __builtin_amdgcn_s_setprio(1);                                                     \
    _Pragma("unroll") for (int m = 0; m < 4; m++) _Pragma("unroll")                    \
        for (int n = 0; n < 4; n++) acc[m][n] =                                        \
            __builtin_amdgcn_mfma_f32_16x16x32_bf16(af[m], bf4[n], acc[m][n], 0, 0, 0);\
    __builtin_amdgcn_s_setprio(0);                                                     \
    BAR();                                                                             \
    /* P2: kh0 rows 64-127 (reuse bf4) | stage (tu+1).B-kh1 | W1 */                    \
    _Pragma("unroll") for (int m = 0; m < 4; m++) af[m] = LF2(PA, 4096 + m * 1024);    \
    if ((tu) + 1 < ntk) stage_half<KD>(Bt, col0, ((tu) + 1) * 64 + 32, (NBEL) + 24576, t);\
    BAR();                                                                             \
    LGKM0();                                                                           \
    __builtin_amdgcn_s_setprio(1);                                                     \
    _Pragma("unroll") for (int m = 0; m < 4; m++) _Pragma("unroll")                    \
        for (int n = 0; n < 4; n++) acc[m + 4][n] =                                    \
            __builtin_amdgcn_mfma_f32_16x16x32_bf16(af[m], bf4[n], acc[m + 4][n], 0, 0, 0);\
    __builtin_amdgcn_s_setprio(0);                                                     \
    if ((tu) < ntk - 1) VMW8();                                                        \
    else VMW0();                                                                       \
    BAR();                                                                             \
    /* P3: kh1 rows 0-63 x n0-3 | stage (tu+2).A-kh0 (kh0 dead after P2) */            \
    _Pragma("unroll") for (int m = 0; m < 4; m++) af[m] = LF2(PA, 16384 + m * 1024);   \
    _Pragma("unroll") for (int n = 0; n < 4; n++) bf4[n] = LF2(PB, 16384 + n * 1024);  \
    if ((tu) + 2 < ntk) stage_half<KD>(A, row0, ((tu) + 2) * 64, (CBEL) + 0, t);       \
    BAR();                                                                             \
    LGKM0();                                                                           \
    __builtin_amdgcn_s_setprio(1);                                                     \
    _Pragma("unroll") for (int m = 0; m < 4; m++) _Pragma("unroll")                    \
        for (int n = 0; n < 4; n++) acc[m][n] =                                        \
            __builtin_amdgcn_mfma_f32_16x16x32_bf16(af[m], bf4[n], acc[m][n], 0, 0, 0);\
    __builtin_amdgcn_s_setprio(0);                                                     \
    BAR();                                                                             \
    /* P4: kh1 rows 64-127 | stage (tu+2).B-kh0 | W2 */                                \
    _Pragma("unroll") for (int m = 0; m < 4; m++) af[m] =                              \
        LF2(PA, 16384 + 4096 + m * 1024);                                              \
    if ((tu) + 2 < ntk) stage_half<KD>(Bt, col0, ((tu) + 2) * 64, (CBEL) + 16384, t);  \
    BAR();                                                                             \
    LGKM0();                                                                           \
    __builtin_amdgcn_s_setprio(1);                                                     \
    _Pragma("unroll") for (int m = 0; m < 4; m++) _Pragma("unroll")                    \
        for (int n = 0; n < 4; n++) acc[m + 4][n] =                                    \
            __builtin_amdgcn_mfma_f32_16x16x32_bf16(af[m], bf4[n], acc[m + 4][n], 0, 0, 0);\
    __builtin_amdgcn_s_setprio(0);                                                     \
    if ((tu) < ntk - 2) VMW8();                                                        \
    else if ((tu) == ntk - 2) VMW4();                                                  \
    BAR();                                                                             \
  }

template <int MM, int N, int KD, bool OUT_BF16>
__global__ __launch_bounds__(512, 2) void gemm256(const bfu* __restrict__ A,
                                                  const bfu* __restrict__ Bt,
                                                  const float* __restrict__ bias,
                                                  void* __restrict__ Cptr) {
  __shared__ bfu lds[2 * 4 * 8192];  // 128 KiB
  const int t = threadIdx.x;
  const int lane = t & 63, wid = t >> 6;
  const int wr = wid >> 2, wc = wid & 3;
  const int lr = lane & 15, lg = lane >> 4;
  const int cpx = gridDim.x >> 3;
  const int li = (blockIdx.x & 7) * cpx + (blockIdx.x >> 3);
  const int row0 = (li % (MM / 256)) * 256;
  const int col0 = (li / (MM / 256)) * 256;
  constexpr int ntk = KD / 64;
  const int abase = ((wr * 128 + lr) * 64 + lg * 16) ^ (((lr >> 1) & 3) << 4);
  const int bbase = ((wc * 64 + lr) * 64 + lg * 16) ^ (((lr >> 1) & 3) << 4);

  char* const lb = reinterpret_cast<char*>(lds);
  const char* const pA0 = lb + abase;
  const char* const pA1 = lb + 65536 + abase;
  const char* const pB0 = lb + 32768 + bbase;
  const char* const pB1 = lb + 65536 + 32768 + bbase;

  fx4 acc[8][4] = {};

  // prologue: tile0 all 4 halves + tile1 kh0 halves = 12 loads; drain oldest 4.
  stage_half<KD>(A, row0, 0, lds + 0, t);
  stage_half<KD>(Bt, col0, 0, lds + 16384, t);
  stage_half<KD>(A, row0, 32, lds + 8192, t);
  stage_half<KD>(Bt, col0, 32, lds + 24576, t);
  stage_half<KD>(A, row0, 64, lds + 32768 + 0, t);
  stage_half<KD>(Bt, col0, 64, lds + 32768 + 16384, t);
  VMW8();
  BAR();

  for (int tau2 = 0; tau2 < ntk; tau2 += 2) {
    KTILE(pA0, pB0, lds, lds + 32768, tau2);
    KTILE(pA1, pB1, lds + 32768, lds, tau2 + 1);
  }

  // epilogue: C/D layout col=lane&15, row=(lane>>4)*4+reg
  float bv[4];
#pragma unroll
  for (int n = 0; n < 4; n++) bv[n] = bias[col0 + wc * 64 + n * 16 + lr];
#pragma unroll
  for (int m = 0; m < 8; m++)
#pragma unroll
    for (int n = 0; n < 4; n++)
#pragma unroll
      for (int r = 0; r < 4; r++) {
        const int row = row0 + wr * 128 + m * 16 + lg * 4 + r;
        const int col = col0 + wc * 64 + n * 16 + lr;
        const float v = acc[m][n][r] + bv[n];
        if constexpr (OUT_BF16)
          ((bfu*)Cptr)[(size_t)row * N + col] = f2bf(v);
        else
          ((float*)Cptr)[(size_t)row * N + col] = v;
      }
}

// ---------------- depthwise causal conv K=4, sliding window ----------------
__global__ __launch_bounds__(256) void dwconv_slide(const bfu* __restrict__ xe,
                                                    const float* __restrict__ cw,
                                                    const float* __restrict__ cb,
                                                    bfu* __restrict__ y) {
  const int nchunk = L_ / LCH;
  const int b = blockIdx.x / nchunk;
  const int l0 = (blockIdx.x % nchunk) * LCH;
  const int cg = threadIdx.x << 3;

  float w[4][8], bias8[8];
#pragma unroll
  for (int tt = 0; tt < 4; tt++) {
    fx4 w0 = *(const fx4*)(cw + tt * C_ + cg);
    fx4 w1 = *(const fx4*)(cw + tt * C_ + cg + 4);
#pragma unroll
    for (int i = 0; i < 4; i++) {
      w[tt][i] = w0[i];
      w[tt][i + 4] = w1[i];
    }
  }
  {
    fx4 c0 = *(const fx4*)(cb + cg), c1 = *(const fx4*)(cb + cg + 4);
#pragma unroll
    for (int i = 0; i < 4; i++) {
      bias8[i] = c0[i];
      bias8[i + 4] = c1[i];
    }
  }

  const size_t base = ((size_t)b * L_ + l0) * C_ + cg;
  s16x8 h0 = {}, h1 = {}, h2 = {};
  if (l0 != 0) {
    h0 = *reinterpret_cast<const s16x8*>(xe + base - 3 * C_);
    h1 = *reinterpret_cast<const s16x8*>(xe + base - 2 * C_);
    h2 = *reinterpret_cast<const s16x8*>(xe + base - 1 * C_);
  }
#pragma unroll
  for (int i = 0; i < LCH; i++) {
    s16x8 h3 = *reinterpret_cast<const s16x8*>(xe + base + (size_t)i * C_);
    s16x8 o;
#pragma unroll
    for (int j = 0; j < 8; j++) {
      float v = bias8[j];
      v = fmaf(bits2f(h0[j]), w[0][j], v);
      v = fmaf(bits2f(h1[j]), w[1][j], v);
      v = fmaf(bits2f(h2[j]), w[2][j], v);
      v = fmaf(bits2f(h3[j]), w[3][j], v);
      o[j] = (short)f2bf(v);
    }
    *reinterpret_cast<s16x8*>(y + base + (size_t)i * C_) = o;
    h0 = h1;
    h1 = h2;
    h2 = h3;
  }
}

extern "C" void kernel_launch(void* const* d_in, const int* in_sizes, int n_in,
                              void* d_out, int out_size, void* d_ws, size_t ws_size,
                              hipStream_t stream) {
  const float* x = (const float*)d_in[0];
  const float* W_exp = (const float*)d_in[1];
  const float* b_exp = (const float*)d_in[2];
  const float* cw = (const float*)d_in[3];
  const float* cb = (const float*)d_in[4];
  const float* W_cmp = (const float*)d_in[5];
  const float* b_cmp = (const float*)d_in[6];
  float* out = (float*)d_out;

  char* ws = (char*)d_ws;
  bfu* wexp_t = (bfu*)(ws);                // [C][D] bf16, 4 MiB
  bfu* wcmp_t = (bfu*)(ws + (4u << 20));   // [D][C] bf16, 4 MiB
  bfu* xb = (bfu*)(ws + (8u << 20));       // [M][D] bf16, 32 MiB
  bfu* xe = (bfu*)(ws + (40u << 20));      // [M][C] bf16, 64 MiB
  bfu* y = (bfu*)(ws + (104u << 20));      // [M][C] bf16, 64 MiB

  cvt_f32_bf16<<<2048, 256, 0, stream>>>(x, xb, M_ * D_ / 8);
  transpose_cvt<D_, C_><<<dim3(C_ / 32, D_ / 32), dim3(32, 8), 0, stream>>>(W_exp, wexp_t);
  transpose_cvt<C_, D_><<<dim3(D_ / 32, C_ / 32), dim3(32, 8), 0, stream>>>(W_cmp, wcmp_t);
  // expand GEMM: xe = x @ W_exp + b_exp
  gemm256<M_, C_, D_, true><<<512, 512, 0, stream>>>(xb, wexp_t, b_exp, xe);
  // conv
  dwconv_slide<<<B_ * (L_ / LCH), 256, 0, stream>>>(xe, cw, cb, y);
  // compress GEMM: out = y @ W_cmp + b_cmp
  gemm256<M_, D_, C_, false><<<256, 512, 0, stream>>>(y, wcmp_t, b_cmp, out);
}